// Round 1
// baseline (117.119 us; speedup 1.0000x reference)
//
#include <hip/hip_runtime.h>

// Pendulum2 DAE closed-form per-row solve.
// Row: coords = [x0 x1 x2 x3 | v0 v1 v2 v3]  ->  out = [v0..v3 | a0..a3]
// Derivation (M0=M1=G=10, Minv = 0.1*I):
//   a = x0-x2, b = x1-x3
//   L00 = 0.4(x0^2+x1^2); L01 = 0.4(x0*a + x1*b); L11 = 0.8(a^2+b^2)
//   R1  = -20*x1 + 2(v0^2+v1^2); R2 = 2((v0-v2)^2+(v1-v3)^2)
//   [L00 L01; L01 L11] lam = [R1; R2]   (2x2 Cramer, fp64 for det robustness)
//   acc = 0.1 * (F - phi_q^T lam), F = (0,-100,0,-100)
__global__ __launch_bounds__(256) void pendulum_dae_kernel(
    const float* __restrict__ coords, float* __restrict__ out, int n) {
  int i = blockIdx.x * blockDim.x + threadIdx.x;
  if (i >= n) return;

  const float4* in4 = (const float4*)coords;
  float4 xv = in4[2 * i];      // x0 x1 x2 x3
  float4 vv = in4[2 * i + 1];  // v0 v1 v2 v3

  float x0 = xv.x, x1 = xv.y, x2 = xv.z, x3 = xv.w;
  float v0 = vv.x, v1 = vv.y, v2 = vv.z, v3 = vv.w;

  float da = x0 - x2, db = x1 - x3;
  float dv0 = v0 - v2, dv1 = v1 - v3;

  float L00 = 0.4f * (x0 * x0 + x1 * x1);
  float L01 = 0.4f * (x0 * da + x1 * db);
  float L11 = 0.8f * (da * da + db * db);

  float R1 = -20.0f * x1 + 2.0f * (v0 * v0 + v1 * v1);
  float R2 = 2.0f * (dv0 * dv0 + dv1 * dv1);

  // 2x2 solve in fp64 (cheap; protects near-singular rows from cancellation)
  double dL00 = (double)L00, dL01 = (double)L01, dL11 = (double)L11;
  double det = dL00 * dL11 - dL01 * dL01;
  double inv = 1.0 / det;
  float lam1 = (float)((dL11 * (double)R1 - dL01 * (double)R2) * inv);
  float lam2 = (float)((dL00 * (double)R2 - dL01 * (double)R1) * inv);

  float aR0 = -(2.0f * x0 * lam1 + 2.0f * da * lam2);
  float aR1 = -100.0f - (2.0f * x1 * lam1 + 2.0f * db * lam2);
  float aR2 = 2.0f * da * lam2;
  float aR3 = -100.0f + 2.0f * db * lam2;

  float4* out4 = (float4*)out;
  out4[2 * i] = vv;
  out4[2 * i + 1] =
      make_float4(0.1f * aR0, 0.1f * aR1, 0.1f * aR2, 0.1f * aR3);
}

extern "C" void kernel_launch(void* const* d_in, const int* in_sizes, int n_in,
                              void* d_out, int out_size, void* d_ws,
                              size_t ws_size, hipStream_t stream) {
  // d_in[0] = t (unused, size 1), d_in[1] = coords (bs*8 fp32)
  const float* coords = (const float*)d_in[1];
  float* out = (float*)d_out;
  int n = in_sizes[1] / 8;  // rows
  int block = 256;
  int grid = (n + block - 1) / block;
  pendulum_dae_kernel<<<grid, block, 0, stream>>>(coords, out, n);
}